// Round 6
// baseline (361.416 us; speedup 1.0000x reference)
//
#include <hip/hip_runtime.h>
#include <hip/hip_bf16.h>
#include <stdint.h>
#include <stddef.h>

// Problem constants (match reference)
#define NB 16       // genes
#define NS 4096     // splice sites per gene
#define NSA 4098    // augmented sites (incl. gene_start, gene_end)
#define NC 512      // channels per site rep
#define NJ 4096     // junctions per gene
#define NT 64       // transcripts per gene
#define NKJ 32      // junctions per transcript
#define KD 1024     // 2*NC = MLP in/hidden dim

// Compaction: only junctions referenced by transcript_junctions need pot.
#define NJC 2048                 // compact region stride per gene
#define NMC (NB * NJC)           // 32768 compact rows (worst case)

// prep0 kernel block ranges (blockDim = 1024)
#define P0_COMPACT_BLKS NB                  // 16: per-gene compaction
#define P0_W_BLKS 2048                      // weight transpose tiles
#define P0_POT_BLKS 8                       // pot zeroing (32768 floats)

typedef __hip_bfloat16 bf16;
typedef __attribute__((ext_vector_type(8))) short bf16x8;  // 8 bf16 = 4 VGPRs
typedef __attribute__((ext_vector_type(4))) float f32x4;

// GEMM tile geometry: BM=128 x BN=128 x BK=64, 4 waves (2x2),
// 4x4 16x16x32 MFMA per wave. LDS 16B-granule XOR swizzle: logical
// (row m, granule g) stored at slot m*8 + (g ^ (m&7)).
// NOTE (round-4 lesson): 16x16 fragment reads (16 rows x 4 per-quad
// granules per wave) are conflict-free on this layout (HW-verified, r0);
// 32x32 reads (32 rows x 1 granule) hit ~4-way conflicts (6.8M, r4). Keep 16x16.
#define BM 128
#define BN 128
#define BK 64

// async global->LDS, 16B per lane. Global address is PER-LANE (gather ok);
// LDS dest = wave-uniform base + lane*16.
__device__ __forceinline__ void gload_lds16(const bf16* g, bf16* l) {
  __builtin_amdgcn_global_load_lds(
      (const __attribute__((address_space(1))) void*)g,
      (__attribute__((address_space(3))) void*)l, 16, 0, 0);
}

// XCD-aware tile swizzle: bid = hi*64 + c*8 + lo -> row_idx = hi*8+lo,
// col_idx = c. Bijective for grids that are a multiple of 64 blocks.
__device__ __forceinline__ void tile_from_bid(int bid, int& row_idx,
                                              int& col_idx) {
  row_idx = ((bid >> 6) << 3) | (bid & 7);
  col_idx = (bid >> 3) & 7;
}

// Dynamic row-tile -> (gene, local tile) map through per-gene counts.
__device__ __forceinline__ int map_tile(const int* __restrict__ cnt,
                                        int row_tile, int& b_out) {
  int at = 0;
#pragma unroll
  for (int b = 0; b < NB; b++) {
    const int g = (cnt[b] + (BM - 1)) >> 7;  // tiles for gene b
    if (row_tile < at + g) { b_out = b; return row_tile - at; }
    at += g;
  }
  b_out = -1;
  return 0;
}

// ---------------------------------------------------------------------------
// prep0: fused independent prep work, disjoint block ranges (blockDim 1024):
//   [0, 16)        : per-gene junction compaction
//   [16, 16+2048)  : W1/W2 transpose+cast 32x32 tiles -> W1t/W2t
//   [2064, 2072)   : zero pot (32768 floats)
__global__ __launch_bounds__(1024) void prep0_kernel(
    const int* __restrict__ tj,       // [16,64,32] flat
    int* __restrict__ rows_list,      // [NB*NJC]
    int* __restrict__ pmap,           // [NB*NJ]
    int* __restrict__ cnt,            // [NB]
    const float* __restrict__ W1, bf16* __restrict__ W1t,
    const float* __restrict__ W2, bf16* __restrict__ W2t,
    float* __restrict__ pot) {
  const int bid = blockIdx.x;
  const int tid = threadIdx.x;  // 0..1023
  if (bid < P0_COMPACT_BLKS) {
    // ---- compaction: one block per gene ----
    const int b = bid;
    const int lane = tid & 63;
    const int wv = tid >> 6;  // 0..15
    __shared__ unsigned char flg[NJ];
    __shared__ int wtot[16];

    *(uint32_t*)&flg[tid * 4] = 0u;
    __syncthreads();

#pragma unroll
    for (int k = 0; k < 2; k++) {
      const int j = tj[b * (NT * NKJ) + tid * 2 + k];
      flg[j] = 1;  // benign races: same value
    }
    if (tid == 0) flg[0] = 1;  // pad rows gather junction 0's sites
    __syncthreads();

    const int j0 = tid * 4;
    const int f0 = flg[j0], f1 = flg[j0 + 1], f2 = flg[j0 + 2],
              f3 = flg[j0 + 3];
    const int ls = f0 + f1 + f2 + f3;

    int x = ls;
#pragma unroll
    for (int o = 1; o < 64; o <<= 1) {
      const int y = __shfl_up(x, o);
      if (lane >= o) x += y;
    }
    if (lane == 63) wtot[wv] = x;
    __syncthreads();

    int woff = 0, total = 0;
#pragma unroll
    for (int w = 0; w < 16; w++) {
      const int t = wtot[w];
      if (w < wv) woff += t;
      total += t;
    }
    int p = woff + x - ls;

    int* rl = rows_list + (size_t)b * NJC;
    int* pm = pmap + (size_t)b * NJ;
    if (f0) { rl[p] = j0;     pm[j0]     = p; p++; }
    if (f1) { rl[p] = j0 + 1; pm[j0 + 1] = p; p++; }
    if (f2) { rl[p] = j0 + 2; pm[j0 + 2] = p; p++; }
    if (f3) { rl[p] = j0 + 3; pm[j0 + 3] = p; p++; }

    for (int i = total + tid; i < NJC; i += 1024) rl[i] = 0;
    if (tid == 0) cnt[b] = total;
  } else if (bid < P0_COMPACT_BLKS + P0_W_BLKS) {
    // ---- weight transpose+cast, 1024 threads = one 32x32 tile ----
    __shared__ bf16 tile[32][33];
    const int pos0 = bid - P0_COMPACT_BLKS;
    const float* W = (pos0 >= 1024) ? W2 : W1;
    bf16* Wt = (pos0 >= 1024) ? W2t : W1t;
    const int pos = pos0 & 1023;
    const int n0 = (pos & 31) * 32;
    const int k0 = (pos >> 5) * 32;
    const int c = tid & 31;
    const int r = tid >> 5;  // 0..31
    tile[r][c] = __float2bfloat16(W[(size_t)(k0 + r) * KD + (n0 + c)]);
    __syncthreads();
    Wt[(size_t)(n0 + r) * KD + (k0 + c)] = tile[c][r];
  } else {
    // ---- zero pot: 8 blocks x 1024 threads x 4 floats = 32768 ----
    const int i = (bid - (P0_COMPACT_BLKS + P0_W_BLKS)) * 4096 + tid * 4;
    *(f32x4*)(pot + i) = (f32x4){0.f, 0.f, 0.f, 0.f};
  }
}

// ---------------------------------------------------------------------------
// GEMM1 with fused gather + f32->bf16 conversion: compact row r of gene gb ->
// jid = rows_list[gb*NJC + r]; A row = concat(bf16(ssr[don[jid]]),
// bf16(ssr[acc[jid]])), gathered DIRECTLY from the f32 site table (no aug
// round trip). A is reg-staged (f32x4 loads -> cvt -> swizzled ds_write);
// B (W1t) stays on async global_load_lds. C = relu(A @ W1t^T + b1) -> bf16.
__global__ __launch_bounds__(256, 2) void gemm1_gather_kernel(
    const float* __restrict__ ssr, const float* __restrict__ gstart,
    const float* __restrict__ gend, const int* __restrict__ don,
    const int* __restrict__ acc, const int* __restrict__ rows_list,
    const int* __restrict__ cnt, const bf16* __restrict__ Bt,
    const float* __restrict__ bias, bf16* __restrict__ Cout) {
  __shared__ __align__(16) bf16 As[BM * BK];
  __shared__ __align__(16) bf16 Bs[BN * BK];
  const int tid = threadIdx.x;
  const int wave = tid >> 6;
  const int lane = tid & 63;
  int row_idx, col_idx;
  tile_from_bid(blockIdx.x, row_idx, col_idx);
  int gb;
  const int lt = map_tile(cnt, row_idx, gb);
  if (gb < 0) return;  // past the live tiles
  const int grow0 = gb * NJC + lt * BM;  // global compact row base
  const int col0 = col_idx * BN;
  const int wm = wave & 1;
  const int wn = wave >> 1;
  const int q = lane >> 4;
  const int rr = lane & 15;

  // staging descriptors: LDS slot L covers logical (row m, granule g)
  int mm[4], gg[4];
#pragma unroll
  for (int i = 0; i < 4; i++) {
    int L = wave * 256 + i * 64 + lane;
    int m = L >> 3;
    int g = (L & 7) ^ (m & 7);
    mm[i] = m; gg[i] = g;
  }

  // per-lane gathered A row base pointers into the f32 site data
  const float* dp[4];
  const float* ap[4];
#pragma unroll
  for (int i = 0; i < 4; i++) {
    const int jid = rows_list[grow0 + mm[i]];
    const int sd = don[gb * NJ + jid];
    const int sa = acc[gb * NJ + jid];
    dp[i] = (sd < NS) ? ssr + ((size_t)gb * NS + sd) * NC
                      : ((sd == NS) ? gstart : gend);
    ap[i] = (sa < NS) ? ssr + ((size_t)gb * NS + sa) * NC
                      : ((sa == NS) ? gstart : gend);
  }

  f32x4 acc4[4][4] = {};

  for (int kt = 0; kt < KD / BK; ++kt) {
    const int ko = (kt & 7) * BK;  // offset within the 512-wide half
    // B: async DMA staging
#pragma unroll
    for (int i = 0; i < 4; i++) {
      gload_lds16(Bt + ((size_t)(col0 + mm[i]) * KD + kt * BK + gg[i] * 8),
                  Bs + (size_t)(wave * 256 + i * 64) * 8);
    }
    // A: reg-staged gather (f32) -> bf16 -> swizzled LDS slot
    f32x4 v0[4], v1[4];
#pragma unroll
    for (int i = 0; i < 4; i++) {
      const float* base = ((kt < 8) ? dp[i] : ap[i]) + ko + gg[i] * 8;
      v0[i] = *(const f32x4*)(base);
      v1[i] = *(const f32x4*)(base + 4);
    }
#pragma unroll
    for (int i = 0; i < 4; i++) {
      union { bf16x8 v; bf16 e[8]; } u;
      u.e[0] = __float2bfloat16(v0[i].x); u.e[1] = __float2bfloat16(v0[i].y);
      u.e[2] = __float2bfloat16(v0[i].z); u.e[3] = __float2bfloat16(v0[i].w);
      u.e[4] = __float2bfloat16(v1[i].x); u.e[5] = __float2bfloat16(v1[i].y);
      u.e[6] = __float2bfloat16(v1[i].z); u.e[7] = __float2bfloat16(v1[i].w);
      *(bf16x8*)(As + (size_t)(wave * 256 + i * 64 + lane) * 8) = u.v;
    }
    __syncthreads();
#pragma unroll
    for (int kk = 0; kk < 2; ++kk) {
      bf16x8 afr[4], bfr[4];
      const int g = kk * 4 + q;
#pragma unroll
      for (int mt = 0; mt < 4; mt++) {
        int m = wm * 64 + mt * 16 + rr;
        afr[mt] = *(const bf16x8*)(As + (m * 8 + (g ^ (m & 7))) * 8);
      }
#pragma unroll
      for (int nt = 0; nt < 4; nt++) {
        int n = wn * 64 + nt * 16 + rr;
        bfr[nt] = *(const bf16x8*)(Bs + (n * 8 + (g ^ (n & 7))) * 8);
      }
#pragma unroll
      for (int mt = 0; mt < 4; mt++)
#pragma unroll
        for (int nt = 0; nt < 4; nt++)
          acc4[mt][nt] = __builtin_amdgcn_mfma_f32_16x16x32_bf16(
              afr[mt], bfr[nt], acc4[mt][nt], 0, 0, 0);
    }
    __syncthreads();
  }

  // Epilogue. C/D layout: col = lane&15, row = quad*4 + reg
#pragma unroll
  for (int nt = 0; nt < 4; nt++) {
    const int col = col0 + wn * 64 + nt * 16 + rr;
    const float bv = bias[col];
#pragma unroll
    for (int mt = 0; mt < 4; mt++) {
      const int rbase = grow0 + wm * 64 + mt * 16 + q * 4;
#pragma unroll
      for (int rg = 0; rg < 4; rg++) {
        float v = fmaxf(acc4[mt][nt][rg] + bv, 0.f);
        Cout[(size_t)(rbase + rg) * KD + col] = __float2bfloat16(v);
      }
    }
  }
}

// ---------------------------------------------------------------------------
// GEMM2: pot contribution = relu(H1 @ W2t^T + b2) @ w3, atomicAdd per row.
__global__ __launch_bounds__(256, 2) void gemm2_kernel(
    const bf16* __restrict__ A, const int* __restrict__ cnt,
    const bf16* __restrict__ Bt, const float* __restrict__ bias,
    const float* __restrict__ w3, float* __restrict__ pot) {
  __shared__ __align__(16) bf16 As[BM * BK];
  __shared__ __align__(16) bf16 Bs[BN * BK];
  const int tid = threadIdx.x;
  const int wave = tid >> 6;
  const int lane = tid & 63;
  int row_idx, col_idx;
  tile_from_bid(blockIdx.x, row_idx, col_idx);
  int gb;
  const int lt = map_tile(cnt, row_idx, gb);
  if (gb < 0) return;
  const int grow0 = gb * NJC + lt * BM;
  const int col0 = col_idx * BN;
  const int wm = wave & 1;
  const int wn = wave >> 1;
  const int q = lane >> 4;
  const int rr = lane & 15;

  int mm[4], gg[4];
#pragma unroll
  for (int i = 0; i < 4; i++) {
    int L = wave * 256 + i * 64 + lane;
    int m = L >> 3;
    int g = (L & 7) ^ (m & 7);
    mm[i] = m; gg[i] = g;
  }

  f32x4 acc4[4][4] = {};

  for (int kt = 0; kt < KD / BK; ++kt) {
#pragma unroll
    for (int i = 0; i < 4; i++) {
      gload_lds16(A + ((size_t)(grow0 + mm[i]) * KD + kt * BK + gg[i] * 8),
                  As + (size_t)(wave * 256 + i * 64) * 8);
      gload_lds16(Bt + ((size_t)(col0 + mm[i]) * KD + kt * BK + gg[i] * 8),
                  Bs + (size_t)(wave * 256 + i * 64) * 8);
    }
    __syncthreads();
#pragma unroll
    for (int kk = 0; kk < 2; ++kk) {
      bf16x8 afr[4], bfr[4];
      const int g = kk * 4 + q;
#pragma unroll
      for (int mt = 0; mt < 4; mt++) {
        int m = wm * 64 + mt * 16 + rr;
        afr[mt] = *(const bf16x8*)(As + (m * 8 + (g ^ (m & 7))) * 8);
      }
#pragma unroll
      for (int nt = 0; nt < 4; nt++) {
        int n = wn * 64 + nt * 16 + rr;
        bfr[nt] = *(const bf16x8*)(Bs + (n * 8 + (g ^ (n & 7))) * 8);
      }
#pragma unroll
      for (int mt = 0; mt < 4; mt++)
#pragma unroll
        for (int nt = 0; nt < 4; nt++)
          acc4[mt][nt] = __builtin_amdgcn_mfma_f32_16x16x32_bf16(
              afr[mt], bfr[nt], acc4[mt][nt], 0, 0, 0);
    }
    __syncthreads();
  }

  float bv[4], wv[4];
#pragma unroll
  for (int nt = 0; nt < 4; nt++) {
    const int col = col0 + wn * 64 + nt * 16 + rr;
    bv[nt] = bias[col];
    wv[nt] = w3[col];
  }
#pragma unroll
  for (int mt = 0; mt < 4; mt++) {
#pragma unroll
    for (int rg = 0; rg < 4; rg++) {
      float s = 0.f;
#pragma unroll
      for (int nt = 0; nt < 4; nt++)
        s += fmaxf(acc4[mt][nt][rg] + bv[nt], 0.f) * wv[nt];
      s += __shfl_xor(s, 1);
      s += __shfl_xor(s, 2);
      s += __shfl_xor(s, 4);
      s += __shfl_xor(s, 8);
      if (rr == 0) {
        int row = grow0 + wm * 64 + mt * 16 + q * 4 + rg;
        atomicAdd(&pot[row], s);
      }
    }
  }
}

// ---------------------------------------------------------------------------
// Per-gene transcript potential sum + softmax over T+1 entries.
// pot is compact: junction j of gene b lives at pot[b*NJC + pmap[b*NJ + j]].
__global__ void transcript_softmax_kernel(const float* __restrict__ pot,
                                          const int* __restrict__ tj,
                                          const int* __restrict__ pmap,
                                          const float* __restrict__ b3,
                                          const float* __restrict__ refp,
                                          float* __restrict__ out) {
  const int b = blockIdx.x;
  const int t = threadIdx.x;  // 64 threads = 1 wave
  const int* tjb = tj + ((size_t)b * NT + t) * NKJ;
  const int* pm = pmap + (size_t)b * NJ;
  const float* pb = pot + (size_t)b * NJC;
  float s = 0.f;
#pragma unroll
  for (int k = 0; k < NKJ; k++) s += pb[pm[tjb[k]]];
  s += (float)NKJ * b3[0];
  const float ref = refp[0];
  float m = fmaxf(s, ref);
#pragma unroll
  for (int o = 1; o < 64; o <<= 1) m = fmaxf(m, __shfl_xor(m, o));
  const float e = expf(s - m);
  float denom = e;
#pragma unroll
  for (int o = 1; o < 64; o <<= 1) denom += __shfl_xor(denom, o);
  const float eref = expf(ref - m);
  denom += eref;
  out[b * (NT + 1) + t] = e / denom;
  if (t == 0) out[b * (NT + 1) + NT] = eref / denom;
}

// ---------------------------------------------------------------------------
extern "C" void kernel_launch(void* const* d_in, const int* in_sizes, int n_in,
                              void* d_out, int out_size, void* d_ws,
                              size_t ws_size, hipStream_t stream) {
  const float* ssr    = (const float*)d_in[0];   // [16,4096,512]
  const int*   don    = (const int*)d_in[1];     // [16,4096]
  const int*   acc    = (const int*)d_in[2];     // [16,4096]
  const int*   tj     = (const int*)d_in[3];     // [16,64,32]
  const float* W1     = (const float*)d_in[4];   // [1024,1024]
  const float* b1     = (const float*)d_in[5];   // [1024]
  const float* W2     = (const float*)d_in[6];   // [1024,1024]
  const float* b2     = (const float*)d_in[7];   // [1024]
  const float* W3     = (const float*)d_in[8];   // [1024,1]
  const float* b3     = (const float*)d_in[9];   // [1]
  const float* gstart = (const float*)d_in[10];  // [512]
  const float* gend   = (const float*)d_in[11];  // [512]
  const float* refp   = (const float*)d_in[12];  // [1]
  float* out = (float*)d_out;                    // [16,65]

  // workspace layout (~75 MiB)
  char* ws = (char*)d_ws;
  bf16* W1t = (bf16*)ws;                 ws += (size_t)KD * KD * 2;
  bf16* W2t = (bf16*)ws;                 ws += (size_t)KD * KD * 2;
  bf16* H1  = (bf16*)ws;                 ws += (size_t)NMC * KD * 2;
  float* pot = (float*)ws;               ws += (size_t)NMC * 4;
  int* rows_list = (int*)ws;             ws += (size_t)NB * NJC * 4;
  int* pmap = (int*)ws;                  ws += (size_t)NB * NJ * 4;
  int* cnt = (int*)ws;                   ws += 64;

  prep0_kernel<<<P0_COMPACT_BLKS + P0_W_BLKS + P0_POT_BLKS, 1024, 0, stream>>>(
      tj, rows_list, pmap, cnt, W1, W1t, W2, W2t, pot);

  gemm1_gather_kernel<<<(NMC / BM) * (KD / BN), 256, 0, stream>>>(
      ssr, gstart, gend, don, acc, rows_list, cnt, W1t, b1, H1);

  gemm2_kernel<<<(NMC / BM) * (KD / BN), 256, 0, stream>>>(H1, cnt, W2t, b2,
                                                           W3, pot);

  transcript_softmax_kernel<<<NB, 64, 0, stream>>>(pot, tj, pmap, b3, refp,
                                                   out);
}

// Round 7
// 333.121 us; speedup vs baseline: 1.0849x; 1.0849x over previous
//
#include <hip/hip_runtime.h>
#include <hip/hip_bf16.h>
#include <stdint.h>
#include <stddef.h>

// Problem constants (match reference)
#define NB 16       // genes
#define NS 4096     // splice sites per gene
#define NSA 4098    // augmented sites (incl. gene_start, gene_end)
#define SFS 4104    // sflag per-gene stride (NSA padded to multiple of 8)
#define NC 512      // channels per site rep
#define NJ 4096     // junctions per gene
#define NT 64       // transcripts per gene
#define NKJ 32      // junctions per transcript
#define KD 1024     // 2*NC = MLP in/hidden dim

// Compaction: only junctions referenced by transcript_junctions need pot.
// Per gene: distinct used junctions cnt[b] <= 2048 (avg ~1612). Compact rows
// live at [b*NJC, b*NJC+cnt[b]); GEMMs process ceil(cnt[b]/128) tiles per
// gene via a dynamic tile map (grid = worst case, extra blocks exit early).
#define NJC 2048                 // compact region stride per gene
#define NMC (NB * NJC)           // 32768 compact rows (worst case)

// prep kernel block ranges
#define PREP_W_BLKS 2048                    // weight transpose tiles
#define PREP_AUG_BLKS ((NB * NSA) / 4)      // 16392: aug rows / 4
#define PREP_POT_BLKS 32                    // pot zeroing (32768 floats)

typedef __hip_bfloat16 bf16;
typedef __attribute__((ext_vector_type(8))) short bf16x8;  // 8 bf16 = 4 VGPRs
typedef __attribute__((ext_vector_type(4))) float f32x4;

// GEMM tile geometry: BM=128 x BN=128 x BK=64, 4 waves (2x2),
// 4x4 16x16x32 MFMA per wave. LDS 16B-granule XOR swizzle: logical
// (row m, granule g) stored at slot m*8 + (g ^ (m&7)).
// Session A/B ledger (HW-verified on this problem):
//  - 16x16x32 MFMA + this swizzle: 0 bank conflicts, ~985 TF (r0/r3)
//  - 32x32x16 MFMA on same layout: 6.8M conflicts, regressed (r4)
//  - 256^2 8-phase counted-vmcnt: regressed at K=1024 (r1)
//  - reg-staged f32 gather (no aug table): regressed (r6)
#define BM 128
#define BN 128
#define BK 64

// async global->LDS, 16B per lane. Global address is PER-LANE (gather ok);
// LDS dest = wave-uniform base + lane*16.
__device__ __forceinline__ void gload_lds16(const bf16* g, bf16* l) {
  __builtin_amdgcn_global_load_lds(
      (const __attribute__((address_space(1))) void*)g,
      (__attribute__((address_space(3))) void*)l, 16, 0, 0);
}

// XCD-aware tile swizzle: bid = hi*64 + c*8 + lo -> row_idx = hi*8+lo,
// col_idx = c. Bijective for grids that are a multiple of 64 blocks.
__device__ __forceinline__ void tile_from_bid(int bid, int& row_idx,
                                              int& col_idx) {
  row_idx = ((bid >> 6) << 3) | (bid & 7);
  col_idx = (bid >> 3) & 7;
}

// Dynamic row-tile -> (gene, local tile) map through per-gene counts.
__device__ __forceinline__ int map_tile(const int* __restrict__ cnt,
                                        int row_tile, int& b_out) {
  int at = 0;
#pragma unroll
  for (int b = 0; b < NB; b++) {
    const int g = (cnt[b] + (BM - 1)) >> 7;  // tiles for gene b
    if (row_tile < at + g) { b_out = b; return row_tile - at; }
    at += g;
  }
  b_out = -1;
  return 0;
}

// ---------------------------------------------------------------------------
// Compaction: per gene, mark used junctions (LDS flags), wave-shuffle scan,
// emit compact row list + inverse position map + per-gene count + used-site
// flags. One block per gene.
__global__ __launch_bounds__(1024) void compact_kernel(
    const int* __restrict__ tj,       // [16,64,32] flat
    const int* __restrict__ don,      // [16,4096]
    const int* __restrict__ acc,      // [16,4096]
    int* __restrict__ rows_list,      // [NB*NJC]
    int* __restrict__ pmap,           // [NB*NJ]
    int* __restrict__ cnt,            // [NB]
    unsigned char* __restrict__ sflag) {  // [NB*SFS]
  const int b = blockIdx.x;
  const int tid = threadIdx.x;  // 0..1023
  const int lane = tid & 63;
  const int wv = tid >> 6;  // 0..15
  __shared__ unsigned char flg[NJ];
  __shared__ int wtot[16];

  *(uint32_t*)&flg[tid * 4] = 0u;
  unsigned char* sf = sflag + (size_t)b * SFS;
  ((uint32_t*)sf)[tid] = 0u;
  if (tid < SFS / 4 - 1024) ((uint32_t*)sf)[1024 + tid] = 0u;
  __syncthreads();

#pragma unroll
  for (int k = 0; k < 2; k++) {
    const int j = tj[b * (NT * NKJ) + tid * 2 + k];
    flg[j] = 1;  // benign races: same value
  }
  if (tid == 0) flg[0] = 1;  // pad rows gather junction 0's sites
  __syncthreads();

  const int j0 = tid * 4;
  const int f0 = flg[j0], f1 = flg[j0 + 1], f2 = flg[j0 + 2], f3 = flg[j0 + 3];
  const int ls = f0 + f1 + f2 + f3;

  int x = ls;
#pragma unroll
  for (int o = 1; o < 64; o <<= 1) {
    const int y = __shfl_up(x, o);
    if (lane >= o) x += y;
  }
  if (lane == 63) wtot[wv] = x;
  __syncthreads();

  int woff = 0, total = 0;
#pragma unroll
  for (int w = 0; w < 16; w++) {
    const int t = wtot[w];
    if (w < wv) woff += t;
    total += t;
  }
  int p = woff + x - ls;

  const int* donb = don + (size_t)b * NJ;
  const int* accb = acc + (size_t)b * NJ;
  int* rl = rows_list + (size_t)b * NJC;
  int* pm = pmap + (size_t)b * NJ;
  if (f0) { rl[p] = j0;     pm[j0]     = p; sf[donb[j0]]     = 1; sf[accb[j0]]     = 1; p++; }
  if (f1) { rl[p] = j0 + 1; pm[j0 + 1] = p; sf[donb[j0 + 1]] = 1; sf[accb[j0 + 1]] = 1; p++; }
  if (f2) { rl[p] = j0 + 2; pm[j0 + 2] = p; sf[donb[j0 + 2]] = 1; sf[accb[j0 + 2]] = 1; p++; }
  if (f3) { rl[p] = j0 + 3; pm[j0 + 3] = p; sf[donb[j0 + 3]] = 1; sf[accb[j0 + 3]] = 1; p++; }

  for (int i = total + tid; i < NJC; i += 1024) rl[i] = 0;
  if (tid == 0) cnt[b] = total;
}

// ---------------------------------------------------------------------------
// Fused prep kernel (disjoint block ranges): W transpose+cast; aug table
// (skipping never-gathered rows); pot zeroing.
__global__ void prep_kernel(const float* __restrict__ W1,
                            bf16* __restrict__ W1t,
                            const float* __restrict__ W2,
                            bf16* __restrict__ W2t,
                            const float* __restrict__ ssr,
                            const float* __restrict__ gstart,
                            const float* __restrict__ gend,
                            const unsigned char* __restrict__ sflag,
                            bf16* __restrict__ aug,
                            float* __restrict__ pot) {
  const int bid = blockIdx.x;
  const int tid = threadIdx.x;
  if (bid < PREP_W_BLKS) {
    __shared__ bf16 tile[32][33];
    const float* W = (bid >= 1024) ? W2 : W1;
    bf16* Wt = (bid >= 1024) ? W2t : W1t;
    const int pos = bid & 1023;
    const int n0 = (pos & 31) * 32;
    const int k0 = (pos >> 5) * 32;
    const int c = tid & 31;
    const int r0 = tid >> 5;  // 0..7
#pragma unroll
    for (int i = 0; i < 4; i++) {
      int r = r0 + i * 8;
      tile[r][c] = __float2bfloat16(W[(size_t)(k0 + r) * KD + (n0 + c)]);
    }
    __syncthreads();
#pragma unroll
    for (int i = 0; i < 4; i++) {
      int r = r0 + i * 8;  // n-row of output
      Wt[(size_t)(n0 + r) * KD + (k0 + c)] = tile[c][r];
    }
  } else if (bid < PREP_W_BLKS + PREP_AUG_BLKS) {
    const int row = (bid - PREP_W_BLKS) * 4 + (tid >> 6);  // 0..NB*NSA-1
    const int i = tid & 63;                                 // lane
    const int b = row / NSA;
    const int s = row - b * NSA;
    if (!sflag[(size_t)b * SFS + s]) return;  // wave-uniform skip
    const float* src;
    if (s < NS)       src = ssr + ((size_t)b * NS + s) * NC;
    else if (s == NS) src = gstart;
    else              src = gend;
    f32x4 f0 = *(const f32x4*)(src + 4 * i);
    f32x4 f1 = *(const f32x4*)(src + 256 + 4 * i);
    bf16* dst = aug + (size_t)row * NC;
    union { uint64_t u; bf16 e[4]; } a, b4;
    a.e[0] = __float2bfloat16(f0.x); a.e[1] = __float2bfloat16(f0.y);
    a.e[2] = __float2bfloat16(f0.z); a.e[3] = __float2bfloat16(f0.w);
    b4.e[0] = __float2bfloat16(f1.x); b4.e[1] = __float2bfloat16(f1.y);
    b4.e[2] = __float2bfloat16(f1.z); b4.e[3] = __float2bfloat16(f1.w);
    *(uint64_t*)(dst + 4 * i) = a.u;
    *(uint64_t*)(dst + 256 + 4 * i) = b4.u;
  } else {
    const int i = (bid - (PREP_W_BLKS + PREP_AUG_BLKS)) * 1024 + tid * 4;
    *(f32x4*)(pot + i) = (f32x4){0.f, 0.f, 0.f, 0.f};
  }
}

// ---------------------------------------------------------------------------
// GEMM1 with fused gather via async DMA: compact row r of gene gb ->
// jid = rows_list[gb*NJC + r]; A row = concat(aug[don[jid]], aug[acc[jid]]).
// C = relu(A @ W1t^T + b1) stored bf16. Dynamic tile count via cnt[].
__global__ __launch_bounds__(256, 2) void gemm1_gather_kernel(
    const bf16* __restrict__ aug, const int* __restrict__ don,
    const int* __restrict__ acc, const int* __restrict__ rows_list,
    const int* __restrict__ cnt, const bf16* __restrict__ Bt,
    const float* __restrict__ bias, bf16* __restrict__ Cout) {
  __shared__ __align__(16) bf16 As[BM * BK];
  __shared__ __align__(16) bf16 Bs[BN * BK];
  const int tid = threadIdx.x;
  const int wave = tid >> 6;
  const int lane = tid & 63;
  int row_idx, col_idx;
  tile_from_bid(blockIdx.x, row_idx, col_idx);
  int gb;
  const int lt = map_tile(cnt, row_idx, gb);
  if (gb < 0) return;  // past the live tiles
  const int grow0 = gb * NJC + lt * BM;  // global compact row base
  const int col0 = col_idx * BN;
  const int wm = wave & 1;
  const int wn = wave >> 1;
  const int q = lane >> 4;
  const int rr = lane & 15;

  // staging descriptors: LDS slot L covers logical (row m, granule g)
  int mm[4], gg[4];
#pragma unroll
  for (int i = 0; i < 4; i++) {
    int L = wave * 256 + i * 64 + lane;
    int m = L >> 3;
    int g = (L & 7) ^ (m & 7);
    mm[i] = m; gg[i] = g;
  }

  // per-lane gathered A row base pointers (don half / acc half of K)
  const bf16* dp[4];
  const bf16* ap[4];
#pragma unroll
  for (int i = 0; i < 4; i++) {
    const int jid = rows_list[grow0 + mm[i]];
    dp[i] = aug + ((size_t)gb * NSA + don[gb * NJ + jid]) * NC;
    ap[i] = aug + ((size_t)gb * NSA + acc[gb * NJ + jid]) * NC;
  }

  f32x4 acc4[4][4] = {};

  for (int kt = 0; kt < KD / BK; ++kt) {
    const int ko = (kt & 7) * BK;  // offset within the 512-wide half
#pragma unroll
    for (int i = 0; i < 4; i++) {
      const bf16* abase = (kt < 8) ? dp[i] : ap[i];
      gload_lds16(abase + ko + gg[i] * 8,
                  As + (size_t)(wave * 256 + i * 64) * 8);
      gload_lds16(Bt + ((size_t)(col0 + mm[i]) * KD + kt * BK + gg[i] * 8),
                  Bs + (size_t)(wave * 256 + i * 64) * 8);
    }
    __syncthreads();
#pragma unroll
    for (int kk = 0; kk < 2; ++kk) {
      bf16x8 afr[4], bfr[4];
      const int g = kk * 4 + q;
#pragma unroll
      for (int mt = 0; mt < 4; mt++) {
        int m = wm * 64 + mt * 16 + rr;
        afr[mt] = *(const bf16x8*)(As + (m * 8 + (g ^ (m & 7))) * 8);
      }
#pragma unroll
      for (int nt = 0; nt < 4; nt++) {
        int n = wn * 64 + nt * 16 + rr;
        bfr[nt] = *(const bf16x8*)(Bs + (n * 8 + (g ^ (n & 7))) * 8);
      }
#pragma unroll
      for (int mt = 0; mt < 4; mt++)
#pragma unroll
        for (int nt = 0; nt < 4; nt++)
          acc4[mt][nt] = __builtin_amdgcn_mfma_f32_16x16x32_bf16(
              afr[mt], bfr[nt], acc4[mt][nt], 0, 0, 0);
    }
    __syncthreads();
  }

  // Epilogue. C/D layout: col = lane&15, row = quad*4 + reg
#pragma unroll
  for (int nt = 0; nt < 4; nt++) {
    const int col = col0 + wn * 64 + nt * 16 + rr;
    const float bv = bias[col];
#pragma unroll
    for (int mt = 0; mt < 4; mt++) {
      const int rbase = grow0 + wm * 64 + mt * 16 + q * 4;
#pragma unroll
      for (int rg = 0; rg < 4; rg++) {
        float v = fmaxf(acc4[mt][nt][rg] + bv, 0.f);
        Cout[(size_t)(rbase + rg) * KD + col] = __float2bfloat16(v);
      }
    }
  }
}

// ---------------------------------------------------------------------------
// GEMM2: pot contribution = relu(H1 @ W2t^T + b2) @ w3, atomicAdd per row.
__global__ __launch_bounds__(256, 2) void gemm2_kernel(
    const bf16* __restrict__ A, const int* __restrict__ cnt,
    const bf16* __restrict__ Bt, const float* __restrict__ bias,
    const float* __restrict__ w3, float* __restrict__ pot) {
  __shared__ __align__(16) bf16 As[BM * BK];
  __shared__ __align__(16) bf16 Bs[BN * BK];
  const int tid = threadIdx.x;
  const int wave = tid >> 6;
  const int lane = tid & 63;
  int row_idx, col_idx;
  tile_from_bid(blockIdx.x, row_idx, col_idx);
  int gb;
  const int lt = map_tile(cnt, row_idx, gb);
  if (gb < 0) return;
  const int grow0 = gb * NJC + lt * BM;
  const int col0 = col_idx * BN;
  const int wm = wave & 1;
  const int wn = wave >> 1;
  const int q = lane >> 4;
  const int rr = lane & 15;

  int mm[4], gg[4];
#pragma unroll
  for (int i = 0; i < 4; i++) {
    int L = wave * 256 + i * 64 + lane;
    int m = L >> 3;
    int g = (L & 7) ^ (m & 7);
    mm[i] = m; gg[i] = g;
  }

  f32x4 acc4[4][4] = {};

  for (int kt = 0; kt < KD / BK; ++kt) {
#pragma unroll
    for (int i = 0; i < 4; i++) {
      gload_lds16(A + ((size_t)(grow0 + mm[i]) * KD + kt * BK + gg[i] * 8),
                  As + (size_t)(wave * 256 + i * 64) * 8);
      gload_lds16(Bt + ((size_t)(col0 + mm[i]) * KD + kt * BK + gg[i] * 8),
                  Bs + (size_t)(wave * 256 + i * 64) * 8);
    }
    __syncthreads();
#pragma unroll
    for (int kk = 0; kk < 2; ++kk) {
      bf16x8 afr[4], bfr[4];
      const int g = kk * 4 + q;
#pragma unroll
      for (int mt = 0; mt < 4; mt++) {
        int m = wm * 64 + mt * 16 + rr;
        afr[mt] = *(const bf16x8*)(As + (m * 8 + (g ^ (m & 7))) * 8);
      }
#pragma unroll
      for (int nt = 0; nt < 4; nt++) {
        int n = wn * 64 + nt * 16 + rr;
        bfr[nt] = *(const bf16x8*)(Bs + (n * 8 + (g ^ (n & 7))) * 8);
      }
#pragma unroll
      for (int mt = 0; mt < 4; mt++)
#pragma unroll
        for (int nt = 0; nt < 4; nt++)
          acc4[mt][nt] = __builtin_amdgcn_mfma_f32_16x16x32_bf16(
              afr[mt], bfr[nt], acc4[mt][nt], 0, 0, 0);
    }
    __syncthreads();
  }

  float bv[4], wv[4];
#pragma unroll
  for (int nt = 0; nt < 4; nt++) {
    const int col = col0 + wn * 64 + nt * 16 + rr;
    bv[nt] = bias[col];
    wv[nt] = w3[col];
  }
#pragma unroll
  for (int mt = 0; mt < 4; mt++) {
#pragma unroll
    for (int rg = 0; rg < 4; rg++) {
      float s = 0.f;
#pragma unroll
      for (int nt = 0; nt < 4; nt++)
        s += fmaxf(acc4[mt][nt][rg] + bv[nt], 0.f) * wv[nt];
      s += __shfl_xor(s, 1);
      s += __shfl_xor(s, 2);
      s += __shfl_xor(s, 4);
      s += __shfl_xor(s, 8);
      if (rr == 0) {
        int row = grow0 + wm * 64 + mt * 16 + q * 4 + rg;
        atomicAdd(&pot[row], s);
      }
    }
  }
}

// ---------------------------------------------------------------------------
// Per-gene transcript potential sum + softmax over T+1 entries.
__global__ void transcript_softmax_kernel(const float* __restrict__ pot,
                                          const int* __restrict__ tj,
                                          const int* __restrict__ pmap,
                                          const float* __restrict__ b3,
                                          const float* __restrict__ refp,
                                          float* __restrict__ out) {
  const int b = blockIdx.x;
  const int t = threadIdx.x;  // 64 threads = 1 wave
  const int* tjb = tj + ((size_t)b * NT + t) * NKJ;
  const int* pm = pmap + (size_t)b * NJ;
  const float* pb = pot + (size_t)b * NJC;
  float s = 0.f;
#pragma unroll
  for (int k = 0; k < NKJ; k++) s += pb[pm[tjb[k]]];
  s += (float)NKJ * b3[0];
  const float ref = refp[0];
  float m = fmaxf(s, ref);
#pragma unroll
  for (int o = 1; o < 64; o <<= 1) m = fmaxf(m, __shfl_xor(m, o));
  const float e = expf(s - m);
  float denom = e;
#pragma unroll
  for (int o = 1; o < 64; o <<= 1) denom += __shfl_xor(denom, o);
  const float eref = expf(ref - m);
  denom += eref;
  out[b * (NT + 1) + t] = e / denom;
  if (t == 0) out[b * (NT + 1) + NT] = eref / denom;
}

// ---------------------------------------------------------------------------
extern "C" void kernel_launch(void* const* d_in, const int* in_sizes, int n_in,
                              void* d_out, int out_size, void* d_ws,
                              size_t ws_size, hipStream_t stream) {
  const float* ssr    = (const float*)d_in[0];   // [16,4096,512]
  const int*   don    = (const int*)d_in[1];     // [16,4096]
  const int*   acc    = (const int*)d_in[2];     // [16,4096]
  const int*   tj     = (const int*)d_in[3];     // [16,64,32]
  const float* W1     = (const float*)d_in[4];   // [1024,1024]
  const float* b1     = (const float*)d_in[5];   // [1024]
  const float* W2     = (const float*)d_in[6];   // [1024,1024]
  const float* b2     = (const float*)d_in[7];   // [1024]
  const float* W3     = (const float*)d_in[8];   // [1024,1]
  const float* b3     = (const float*)d_in[9];   // [1]
  const float* gstart = (const float*)d_in[10];  // [512]
  const float* gend   = (const float*)d_in[11];  // [512]
  const float* refp   = (const float*)d_in[12];  // [1]
  float* out = (float*)d_out;                    // [16,65]

  // workspace layout (~140 MiB)
  char* ws = (char*)d_ws;
  bf16* W1t = (bf16*)ws;                 ws += (size_t)KD * KD * 2;
  bf16* W2t = (bf16*)ws;                 ws += (size_t)KD * KD * 2;
  bf16* aug = (bf16*)ws;                 ws += (size_t)NB * NSA * NC * 2;
  bf16* H1  = (bf16*)ws;                 ws += (size_t)NMC * KD * 2;
  float* pot = (float*)ws;               ws += (size_t)NMC * 4;
  int* rows_list = (int*)ws;             ws += (size_t)NB * NJC * 4;
  int* pmap = (int*)ws;                  ws += (size_t)NB * NJ * 4;
  int* cnt = (int*)ws;                   ws += 64;
  unsigned char* sflag = (unsigned char*)ws;  ws += (size_t)NB * SFS;

  compact_kernel<<<NB, 1024, 0, stream>>>(tj, don, acc, rows_list, pmap, cnt,
                                          sflag);

  prep_kernel<<<PREP_W_BLKS + PREP_AUG_BLKS + PREP_POT_BLKS, 256, 0, stream>>>(
      W1, W1t, W2, W2t, ssr, gstart, gend, sflag, aug, pot);

  gemm1_gather_kernel<<<(NMC / BM) * (KD / BN), 256, 0, stream>>>(
      aug, don, acc, rows_list, cnt, W1t, b1, H1);

  gemm2_kernel<<<(NMC / BM) * (KD / BN), 256, 0, stream>>>(H1, cnt, W2t, b2,
                                                           W3, pot);

  transcript_softmax_kernel<<<NB, 64, 0, stream>>>(pot, tj, pmap, b3, refp,
                                                   out);
}